// Round 5
// baseline (142.908 us; speedup 1.0000x reference)
//
#include <hip/hip_runtime.h>

// EdgeClassifier:
//   Hd = zd @ W1[:, :128]^T + b1   (bf16, in ws)     [N_DRUG x 128]
//   Hp = zp @ W1[:, 128:]^T        (bf16, in ws)     [N_PROT x 128]
//   out[e] = W2 . relu(Hd[row[e]] + Hp[col[e]]) + b2
// R5: edge pass with 8 edges/group (16 gathers in flight/lane);
//     hprep persistent + double-buffered LDS (1 barrier/iter).

typedef __attribute__((ext_vector_type(8))) short bhalf8;
typedef __attribute__((ext_vector_type(4))) float f32x4;

__device__ __forceinline__ unsigned bfr(float f) {
    unsigned u = __builtin_bit_cast(unsigned, f);
    return (u + 0x7fffu + ((u >> 16) & 1u)) >> 16;
}
__device__ __forceinline__ unsigned pk2(float a, float b) {
    return bfr(a) | (bfr(b) << 16);
}
__device__ __forceinline__ float bl(unsigned u) { return __builtin_bit_cast(float, u << 16); }
__device__ __forceinline__ float bh(unsigned u) { return __builtin_bit_cast(float, u & 0xffff0000u); }

// ---------- pass A: persistent, double-buffered H-prep ----------
// tile t in [0, nbd) -> drug rows t*64.. ; t in [nbd, nTiles) -> protein
__global__ __launch_bounds__(512, 4) void hprep_p(
    const float* __restrict__ zd, const float* __restrict__ zp,
    const float* __restrict__ W1, const float* __restrict__ b1,
    unsigned short* __restrict__ Hd, unsigned short* __restrict__ Hp,
    int Nd, int Np, int nbd, int nTiles)
{
    __shared__ __align__(16) short sZ[2][64 * 128];   // 2 x 16 KB, XOR-swizzled
    const int tid  = threadIdx.x;
    const int wave = tid >> 6;
    const int lane = tid & 63;
    const int l15  = lane & 15;
    const int lhi  = lane >> 4;
    const int ocol = wave * 16 + l15;

    // both W1 fragment sets (drug: k 0..127, protein: k 128..255)
    bhalf8 bfD[4], bfP[4];
    #pragma unroll
    for (int ks = 0; ks < 4; ++ks) {
        const float4* sd = (const float4*)(W1 + ocol * 256 + ks * 32 + lhi * 8);
        const float4* sp = (const float4*)(W1 + ocol * 256 + 128 + ks * 32 + lhi * 8);
        float4 p = sd[0], q = sd[1], r = sp[0], s = sp[1];
        bhalf8 f, g;
        f[0] = (short)bfr(p.x); f[1] = (short)bfr(p.y);
        f[2] = (short)bfr(p.z); f[3] = (short)bfr(p.w);
        f[4] = (short)bfr(q.x); f[5] = (short)bfr(q.y);
        f[6] = (short)bfr(q.z); f[7] = (short)bfr(q.w);
        g[0] = (short)bfr(r.x); g[1] = (short)bfr(r.y);
        g[2] = (short)bfr(r.z); g[3] = (short)bfr(r.w);
        g[4] = (short)bfr(s.x); g[5] = (short)bfr(s.y);
        g[6] = (short)bfr(s.z); g[7] = (short)bfr(s.w);
        bfD[ks] = f; bfP[ks] = g;
    }
    const float biasD = b1[ocol];

    const int rl = tid >> 3;      // row within tile
    const int ch = tid & 7;       // 16B-chunk group (4 chunks/thread)

    int t = blockIdx.x;
    if (t >= nTiles) return;

    float4 ra[4];
    {   // load tile t into regs
        const bool isP = t >= nbd;
        const float* z = isP ? zp : zd;
        const int N = isP ? Np : Nd;
        const int r0 = (isP ? t - nbd : t) * 64;
        const int grow = min(r0 + rl, N - 1);
        const float4* zr = (const float4*)(z + (size_t)grow * 128);
        #pragma unroll
        for (int q = 0; q < 4; ++q) ra[q] = zr[ch + q * 8];
    }

    int cur = 0;
    for (; t < nTiles; t += gridDim.x) {
        // write current regs -> buf[cur] (swizzled)
        #pragma unroll
        for (int q = 0; q < 4; ++q) {
            const int s = ch + q * 8;
            uint2 w; w.x = pk2(ra[q].x, ra[q].y); w.y = pk2(ra[q].z, ra[q].w);
            int byte = (rl * 256 + s * 8) ^ ((rl & 7) << 4);
            *(uint2*)((char*)sZ[cur] + byte) = w;
        }
        // issue next tile's loads (in flight during MFMA)
        const int tn = t + gridDim.x;
        float4 rb[4];
        if (tn < nTiles) {
            const bool isP = tn >= nbd;
            const float* z = isP ? zp : zd;
            const int N = isP ? Np : Nd;
            const int r0 = (isP ? tn - nbd : tn) * 64;
            const int grow = min(r0 + rl, N - 1);
            const float4* zr = (const float4*)(z + (size_t)grow * 128);
            #pragma unroll
            for (int q = 0; q < 4; ++q) rb[q] = zr[ch + q * 8];
        }
        __syncthreads();   // buf[cur] staged; prior readers of buf[cur^1] done

        const bool isP = t >= nbd;
        const int N = isP ? Np : Nd;
        const int r0 = (isP ? t - nbd : t) * 64;
        unsigned short* H = isP ? Hp : Hd;
        const float bias = isP ? 0.0f : biasD;

        f32x4 acc[4] = {{0.f,0.f,0.f,0.f},{0.f,0.f,0.f,0.f},
                        {0.f,0.f,0.f,0.f},{0.f,0.f,0.f,0.f}};
        #pragma unroll
        for (int ks = 0; ks < 4; ++ks) {
            bhalf8 bf = isP ? bfP[ks] : bfD[ks];
            #pragma unroll
            for (int rt = 0; rt < 4; ++rt) {
                const int row = rt * 16 + l15;
                int byte = (row * 256 + ks * 64 + lhi * 16) ^ ((row & 7) << 4);
                bhalf8 af = *(const bhalf8*)((const char*)sZ[cur] + byte);
                acc[rt] = __builtin_amdgcn_mfma_f32_16x16x32_bf16(af, bf, acc[rt], 0, 0, 0);
            }
        }
        #pragma unroll
        for (int rt = 0; rt < 4; ++rt) {
            #pragma unroll
            for (int i = 0; i < 4; ++i) {
                const int grow = r0 + rt * 16 + lhi * 4 + i;
                if (grow < N)
                    H[(size_t)grow * 128 + ocol] = (unsigned short)bfr(acc[rt][i] + bias);
            }
        }
        #pragma unroll
        for (int q = 0; q < 4; ++q) ra[q] = rb[q];
        cur ^= 1;
    }
}

// ---------- pass B: per-edge gather + relu + dot(W2) ----------
// 16 lanes/edge; 8 edges/group/iter (16 uint4 gathers in flight per lane)
__global__ __launch_bounds__(256, 4) void edge_kernel(
    const unsigned short* __restrict__ Hd, const unsigned short* __restrict__ Hp,
    const int* __restrict__ eli, const float* __restrict__ W2,
    const float* __restrict__ b2, float* __restrict__ out, int E)
{
    const int sub = threadIdx.x & 15;
    const int grp = threadIdx.x >> 4;          // 0..15
    float4 w2a = ((const float4*)W2)[sub * 2];
    float4 w2b = ((const float4*)W2)[sub * 2 + 1];
    const float b2v = b2[0];

    const int EPB = 16 * 8;                    // 128 edges per block-iter
    const int step = gridDim.x * EPB;
    int base = blockIdx.x * EPB;
    if (base >= E) return;

    int row[8], col[8];
    #pragma unroll
    for (int u = 0; u < 8; ++u) {
        const int e = base + grp * 8 + u;
        row[u] = (e < E) ? eli[e] : 0;
        col[u] = (e < E) ? eli[E + e] : 0;
    }

    for (; base < E; base += step) {
        uint4 hd[8], hp[8];
        #pragma unroll
        for (int u = 0; u < 8; ++u) {
            hd[u] = ((const uint4*)(Hd + (size_t)row[u] * 128))[sub];
            hp[u] = ((const uint4*)(Hp + (size_t)col[u] * 128))[sub];
        }
        const int nb = base + step;
        if (nb < E) {
            #pragma unroll
            for (int u = 0; u < 8; ++u) {
                const int e = nb + grp * 8 + u;
                row[u] = (e < E) ? eli[e] : 0;
                col[u] = (e < E) ? eli[E + e] : 0;
            }
        }
        #pragma unroll
        for (int u = 0; u < 8; ++u) {
            float s = 0.f;
            s = fmaf(fmaxf(bl(hd[u].x) + bl(hp[u].x), 0.f), w2a.x, s);
            s = fmaf(fmaxf(bh(hd[u].x) + bh(hp[u].x), 0.f), w2a.y, s);
            s = fmaf(fmaxf(bl(hd[u].y) + bl(hp[u].y), 0.f), w2a.z, s);
            s = fmaf(fmaxf(bh(hd[u].y) + bh(hp[u].y), 0.f), w2a.w, s);
            s = fmaf(fmaxf(bl(hd[u].z) + bl(hp[u].z), 0.f), w2b.x, s);
            s = fmaf(fmaxf(bh(hd[u].z) + bh(hp[u].z), 0.f), w2b.y, s);
            s = fmaf(fmaxf(bl(hd[u].w) + bl(hp[u].w), 0.f), w2b.z, s);
            s = fmaf(fmaxf(bh(hd[u].w) + bh(hp[u].w), 0.f), w2b.w, s);
            s += __shfl_xor(s, 1, 64);
            s += __shfl_xor(s, 2, 64);
            s += __shfl_xor(s, 4, 64);
            s += __shfl_xor(s, 8, 64);
            const int e = base + grp * 8 + u;
            if (sub == 0 && e < E) out[e] = s + b2v;
        }
    }
}

// ---------- fallback: proven R1 kernel ----------
#define TE 64
__global__ __launch_bounds__(512, 4) void ec_fallback(
    const float* __restrict__ zd, const float* __restrict__ zp,
    const int* __restrict__ eli, const float* __restrict__ W1,
    const float* __restrict__ b1, const float* __restrict__ W2,
    const float* __restrict__ b2, float* __restrict__ out,
    int E, int nTiles)
{
    __shared__ __align__(16) short sZ[TE * 256];
    __shared__ float sPart[8][TE];
    const int tid  = threadIdx.x;
    const int wave = tid >> 6;
    const int lane = tid & 63;
    const int l15  = lane & 15;
    const int lhi  = lane >> 4;
    const int ocol = wave * 16 + l15;
    bhalf8 bfrag[8];
    #pragma unroll
    for (int ks = 0; ks < 8; ++ks) {
        const float4* src = (const float4*)(W1 + ocol * 256 + ks * 32 + lhi * 8);
        float4 p = src[0], q = src[1];
        bhalf8 f;
        f[0] = (short)bfr(p.x); f[1] = (short)bfr(p.y);
        f[2] = (short)bfr(p.z); f[3] = (short)bfr(p.w);
        f[4] = (short)bfr(q.x); f[5] = (short)bfr(q.y);
        f[6] = (short)bfr(q.z); f[7] = (short)bfr(q.w);
        bfrag[ks] = f;
    }
    const float b1v = b1[ocol];
    const float w2v = W2[ocol];
    const float b2v = b2[0];
    const int slot = tid >> 5;
    const int lane32 = tid & 31;
    for (int tile = blockIdx.x; tile < nTiles; tile += gridDim.x) {
        const int base = tile * TE;
        __syncthreads();
        #pragma unroll
        for (int r = 0; r < 4; ++r) {
            const int e  = slot * 4 + r;
            const int eg = base + e;
            int drow = 0, pcol = 0;
            if (eg < E) { drow = eli[eg]; pcol = eli[E + eg]; }
            float4 v = ((const float4*)(zd + (size_t)drow * 128))[lane32];
            float4 u = ((const float4*)(zp + (size_t)pcol * 128))[lane32];
            int byte0 = (e * 512 + lane32 * 8) ^ ((e & 7) << 4);
            uint2 pv; pv.x = pk2(v.x, v.y); pv.y = pk2(v.z, v.w);
            *(uint2*)((char*)sZ + byte0) = pv;
            int byte1 = (e * 512 + 256 + lane32 * 8) ^ ((e & 7) << 4);
            uint2 pu; pu.x = pk2(u.x, u.y); pu.y = pk2(u.z, u.w);
            *(uint2*)((char*)sZ + byte1) = pu;
        }
        __syncthreads();
        f32x4 acc[4] = {{0.f,0.f,0.f,0.f},{0.f,0.f,0.f,0.f},
                        {0.f,0.f,0.f,0.f},{0.f,0.f,0.f,0.f}};
        #pragma unroll
        for (int ks = 0; ks < 8; ++ks) {
            const int kb = (ks * 32 + lhi * 8) * 2;
            #pragma unroll
            for (int rt = 0; rt < 4; ++rt) {
                const int row = rt * 16 + l15;
                int byte = (row * 512 + kb) ^ ((row & 7) << 4);
                bhalf8 af = *(const bhalf8*)((const char*)sZ + byte);
                acc[rt] = __builtin_amdgcn_mfma_f32_16x16x32_bf16(af, bfrag[ks], acc[rt], 0, 0, 0);
            }
        }
        #pragma unroll
        for (int rt = 0; rt < 4; ++rt) {
            #pragma unroll
            for (int i = 0; i < 4; ++i) {
                float v = acc[rt][i] + b1v;
                v = fmaxf(v, 0.0f) * w2v;
                v += __shfl_xor(v, 1, 64);
                v += __shfl_xor(v, 2, 64);
                v += __shfl_xor(v, 4, 64);
                v += __shfl_xor(v, 8, 64);
                if (l15 == 0) sPart[wave][rt * 16 + lhi * 4 + i] = v;
            }
        }
        __syncthreads();
        if (tid < TE) {
            const int eg = base + tid;
            if (eg < E) {
                float s = b2v;
                #pragma unroll
                for (int w = 0; w < 8; ++w) s += sPart[w][tid];
                out[eg] = s;
            }
        }
    }
}

extern "C" void kernel_launch(void* const* d_in, const int* in_sizes, int n_in,
                              void* d_out, int out_size, void* d_ws, size_t ws_size,
                              hipStream_t stream) {
    const float* zd = (const float*)d_in[0];
    const float* zp = (const float*)d_in[1];
    const int*   eli = (const int*)d_in[2];
    const float* W1 = (const float*)d_in[3];
    const float* b1 = (const float*)d_in[4];
    const float* W2 = (const float*)d_in[5];
    const float* b2 = (const float*)d_in[6];
    float* out = (float*)d_out;

    const int E  = in_sizes[2] / 2;
    const int nd = in_sizes[0];        // N_DRUG * 128
    const int np = in_sizes[1];        // N_PROT * 128

    const size_t need = ((size_t)nd + (size_t)np) * sizeof(unsigned short);
    if (ws_size >= need) {
        unsigned short* Hd = (unsigned short*)d_ws;
        unsigned short* Hp = Hd + nd;
        const int Nd = nd / 128, Np = np / 128;
        const int nbd = (Nd + 63) / 64, nbp = (Np + 63) / 64;
        const int nTiles = nbd + nbp;
        const int gA = (nTiles + 1) / 2;          // 2 tiles/block -> pipelined
        hipLaunchKernelGGL(hprep_p, dim3(gA), dim3(512), 0, stream,
                           zd, zp, W1, b1, Hd, Hp, Nd, Np, nbd, nTiles);
        hipLaunchKernelGGL(edge_kernel, dim3(2048), dim3(256), 0, stream,
                           Hd, Hp, eli, W2, b2, out, E);
    } else {
        const int nTiles = (E + TE - 1) / TE;
        hipLaunchKernelGGL(ec_fallback, dim3(2048), dim3(512), 0, stream,
                           zd, zp, eli, W1, b1, W2, b2, out, E, nTiles);
    }
}

// Round 6
// 89.217 us; speedup vs baseline: 1.6018x; 1.6018x over previous
//
#include <hip/hip_runtime.h>

// EdgeClassifier:
//   Hd = zd @ W1[:, :128]^T + b1   (bf16, in ws)     [N_DRUG x 128]
//   Hp = zp @ W1[:, 128:]^T        (bf16, in ws)     [N_PROT x 128]
//   out[e] = W2 . relu(Hd[row[e]] + Hp[col[e]]) + b2
// R6: hprep reverted to R4's proven single-pass hprep2 (persistent/dbuf was a
//     barrier-drain trap); edge keeps 8 edges/group, grid 2048 -> 4096 (2x MLP).

typedef __attribute__((ext_vector_type(8))) short bhalf8;
typedef __attribute__((ext_vector_type(4))) float f32x4;

__device__ __forceinline__ unsigned bfr(float f) {
    unsigned u = __builtin_bit_cast(unsigned, f);
    return (u + 0x7fffu + ((u >> 16) & 1u)) >> 16;
}
__device__ __forceinline__ unsigned pk2(float a, float b) {
    return bfr(a) | (bfr(b) << 16);
}
__device__ __forceinline__ float bl(unsigned u) { return __builtin_bit_cast(float, u << 16); }
__device__ __forceinline__ float bh(unsigned u) { return __builtin_bit_cast(float, u & 0xffff0000u); }

// ---------- pass A (fused, non-persistent): H = z @ W1slice^T (+bias) ----------
// one block = 64 rows of one table; blocks [0,nbd) -> drug, [nbd,..) -> protein
__global__ __launch_bounds__(512) void hprep2_kernel(
    const float* __restrict__ zd, const float* __restrict__ zp,
    const float* __restrict__ W1, const float* __restrict__ b1,
    unsigned short* __restrict__ Hd, unsigned short* __restrict__ Hp,
    int Nd, int Np, int nbd)
{
    __shared__ __align__(16) short sZ[64 * 128];   // 16 KB bf16, XOR-swizzled
    const bool isP = blockIdx.x >= nbd;
    const float* z = isP ? zp : zd;
    unsigned short* H = isP ? Hp : Hd;
    const int N    = isP ? Np : Nd;
    const int koff = isP ? 128 : 0;
    const int blk  = isP ? blockIdx.x - nbd : blockIdx.x;

    const int tid  = threadIdx.x;
    const int wave = tid >> 6;
    const int lane = tid & 63;
    const int l15  = lane & 15;
    const int lhi  = lane >> 4;
    const int ocol = wave * 16 + l15;

    bhalf8 bfrag[4];
    #pragma unroll
    for (int ks = 0; ks < 4; ++ks) {
        const float4* src = (const float4*)(W1 + ocol * 256 + koff + ks * 32 + lhi * 8);
        float4 p = src[0], q = src[1];
        bhalf8 f;
        f[0] = (short)bfr(p.x); f[1] = (short)bfr(p.y);
        f[2] = (short)bfr(p.z); f[3] = (short)bfr(p.w);
        f[4] = (short)bfr(q.x); f[5] = (short)bfr(q.y);
        f[6] = (short)bfr(q.z); f[7] = (short)bfr(q.w);
        bfrag[ks] = f;
    }
    const float bias = isP ? 0.0f : b1[ocol];

    const int r0 = blk * 64;

    // stage 64 rows x 128 fp32 -> bf16 LDS (8 threads/row)
    {
        const int rl = tid >> 3;
        const int grow = min(r0 + rl, N - 1);
        const float4* zr = (const float4*)(z + (size_t)grow * 128);
        #pragma unroll
        for (int q = 0; q < 4; ++q) {
            const int s = (tid & 7) + q * 8;
            float4 v = zr[s];
            uint2 w; w.x = pk2(v.x, v.y); w.y = pk2(v.z, v.w);
            int byte = (rl * 256 + s * 8) ^ ((rl & 7) << 4);
            *(uint2*)((char*)sZ + byte) = w;
        }
    }
    __syncthreads();

    f32x4 acc[4] = {{0.f,0.f,0.f,0.f},{0.f,0.f,0.f,0.f},
                    {0.f,0.f,0.f,0.f},{0.f,0.f,0.f,0.f}};
    #pragma unroll
    for (int ks = 0; ks < 4; ++ks) {
        #pragma unroll
        for (int rt = 0; rt < 4; ++rt) {
            const int row = rt * 16 + l15;
            int byte = (row * 256 + ks * 64 + lhi * 16) ^ ((row & 7) << 4);
            bhalf8 af = *(const bhalf8*)((const char*)sZ + byte);
            acc[rt] = __builtin_amdgcn_mfma_f32_16x16x32_bf16(af, bfrag[ks], acc[rt], 0, 0, 0);
        }
    }
    #pragma unroll
    for (int rt = 0; rt < 4; ++rt) {
        #pragma unroll
        for (int i = 0; i < 4; ++i) {
            const int grow = r0 + rt * 16 + lhi * 4 + i;
            if (grow < N)
                H[(size_t)grow * 128 + ocol] = (unsigned short)bfr(acc[rt][i] + bias);
        }
    }
}

// ---------- pass B: per-edge gather + relu + dot(W2) ----------
// 16 lanes/edge; 8 edges/group/iter (16 uint4 gathers in flight per lane)
__global__ __launch_bounds__(256, 4) void edge_kernel(
    const unsigned short* __restrict__ Hd, const unsigned short* __restrict__ Hp,
    const int* __restrict__ eli, const float* __restrict__ W2,
    const float* __restrict__ b2, float* __restrict__ out, int E)
{
    const int sub = threadIdx.x & 15;
    const int grp = threadIdx.x >> 4;          // 0..15
    float4 w2a = ((const float4*)W2)[sub * 2];
    float4 w2b = ((const float4*)W2)[sub * 2 + 1];
    const float b2v = b2[0];

    const int EPB = 16 * 8;                    // 128 edges per block-iter
    const int step = gridDim.x * EPB;
    int base = blockIdx.x * EPB;
    if (base >= E) return;

    int row[8], col[8];
    #pragma unroll
    for (int u = 0; u < 8; ++u) {
        const int e = base + grp * 8 + u;
        row[u] = (e < E) ? eli[e] : 0;
        col[u] = (e < E) ? eli[E + e] : 0;
    }

    for (; base < E; base += step) {
        uint4 hd[8], hp[8];
        #pragma unroll
        for (int u = 0; u < 8; ++u) {
            hd[u] = ((const uint4*)(Hd + (size_t)row[u] * 128))[sub];
            hp[u] = ((const uint4*)(Hp + (size_t)col[u] * 128))[sub];
        }
        const int nb = base + step;
        if (nb < E) {
            #pragma unroll
            for (int u = 0; u < 8; ++u) {
                const int e = nb + grp * 8 + u;
                row[u] = (e < E) ? eli[e] : 0;
                col[u] = (e < E) ? eli[E + e] : 0;
            }
        }
        #pragma unroll
        for (int u = 0; u < 8; ++u) {
            float s = 0.f;
            s = fmaf(fmaxf(bl(hd[u].x) + bl(hp[u].x), 0.f), w2a.x, s);
            s = fmaf(fmaxf(bh(hd[u].x) + bh(hp[u].x), 0.f), w2a.y, s);
            s = fmaf(fmaxf(bl(hd[u].y) + bl(hp[u].y), 0.f), w2a.z, s);
            s = fmaf(fmaxf(bh(hd[u].y) + bh(hp[u].y), 0.f), w2a.w, s);
            s = fmaf(fmaxf(bl(hd[u].z) + bl(hp[u].z), 0.f), w2b.x, s);
            s = fmaf(fmaxf(bh(hd[u].z) + bh(hp[u].z), 0.f), w2b.y, s);
            s = fmaf(fmaxf(bl(hd[u].w) + bl(hp[u].w), 0.f), w2b.z, s);
            s = fmaf(fmaxf(bh(hd[u].w) + bh(hp[u].w), 0.f), w2b.w, s);
            s += __shfl_xor(s, 1, 64);
            s += __shfl_xor(s, 2, 64);
            s += __shfl_xor(s, 4, 64);
            s += __shfl_xor(s, 8, 64);
            const int e = base + grp * 8 + u;
            if (sub == 0 && e < E) out[e] = s + b2v;
        }
    }
}

// ---------- fallback: proven R1 kernel ----------
#define TE 64
__global__ __launch_bounds__(512, 4) void ec_fallback(
    const float* __restrict__ zd, const float* __restrict__ zp,
    const int* __restrict__ eli, const float* __restrict__ W1,
    const float* __restrict__ b1, const float* __restrict__ W2,
    const float* __restrict__ b2, float* __restrict__ out,
    int E, int nTiles)
{
    __shared__ __align__(16) short sZ[TE * 256];
    __shared__ float sPart[8][TE];
    const int tid  = threadIdx.x;
    const int wave = tid >> 6;
    const int lane = tid & 63;
    const int l15  = lane & 15;
    const int lhi  = lane >> 4;
    const int ocol = wave * 16 + l15;
    bhalf8 bfrag[8];
    #pragma unroll
    for (int ks = 0; ks < 8; ++ks) {
        const float4* src = (const float4*)(W1 + ocol * 256 + ks * 32 + lhi * 8);
        float4 p = src[0], q = src[1];
        bhalf8 f;
        f[0] = (short)bfr(p.x); f[1] = (short)bfr(p.y);
        f[2] = (short)bfr(p.z); f[3] = (short)bfr(p.w);
        f[4] = (short)bfr(q.x); f[5] = (short)bfr(q.y);
        f[6] = (short)bfr(q.z); f[7] = (short)bfr(q.w);
        bfrag[ks] = f;
    }
    const float b1v = b1[ocol];
    const float w2v = W2[ocol];
    const float b2v = b2[0];
    const int slot = tid >> 5;
    const int lane32 = tid & 31;
    for (int tile = blockIdx.x; tile < nTiles; tile += gridDim.x) {
        const int base = tile * TE;
        __syncthreads();
        #pragma unroll
        for (int r = 0; r < 4; ++r) {
            const int e  = slot * 4 + r;
            const int eg = base + e;
            int drow = 0, pcol = 0;
            if (eg < E) { drow = eli[eg]; pcol = eli[E + eg]; }
            float4 v = ((const float4*)(zd + (size_t)drow * 128))[lane32];
            float4 u = ((const float4*)(zp + (size_t)pcol * 128))[lane32];
            int byte0 = (e * 512 + lane32 * 8) ^ ((e & 7) << 4);
            uint2 pv; pv.x = pk2(v.x, v.y); pv.y = pk2(v.z, v.w);
            *(uint2*)((char*)sZ + byte0) = pv;
            int byte1 = (e * 512 + 256 + lane32 * 8) ^ ((e & 7) << 4);
            uint2 pu; pu.x = pk2(u.x, u.y); pu.y = pk2(u.z, u.w);
            *(uint2*)((char*)sZ + byte1) = pu;
        }
        __syncthreads();
        f32x4 acc[4] = {{0.f,0.f,0.f,0.f},{0.f,0.f,0.f,0.f},
                        {0.f,0.f,0.f,0.f},{0.f,0.f,0.f,0.f}};
        #pragma unroll
        for (int ks = 0; ks < 8; ++ks) {
            const int kb = (ks * 32 + lhi * 8) * 2;
            #pragma unroll
            for (int rt = 0; rt < 4; ++rt) {
                const int row = rt * 16 + l15;
                int byte = (row * 512 + kb) ^ ((row & 7) << 4);
                bhalf8 af = *(const bhalf8*)((const char*)sZ + byte);
                acc[rt] = __builtin_amdgcn_mfma_f32_16x16x32_bf16(af, bfrag[ks], acc[rt], 0, 0, 0);
            }
        }
        #pragma unroll
        for (int rt = 0; rt < 4; ++rt) {
            #pragma unroll
            for (int i = 0; i < 4; ++i) {
                float v = acc[rt][i] + b1v;
                v = fmaxf(v, 0.0f) * w2v;
                v += __shfl_xor(v, 1, 64);
                v += __shfl_xor(v, 2, 64);
                v += __shfl_xor(v, 4, 64);
                v += __shfl_xor(v, 8, 64);
                if (l15 == 0) sPart[wave][rt * 16 + lhi * 4 + i] = v;
            }
        }
        __syncthreads();
        if (tid < TE) {
            const int eg = base + tid;
            if (eg < E) {
                float s = b2v;
                #pragma unroll
                for (int w = 0; w < 8; ++w) s += sPart[w][tid];
                out[eg] = s;
            }
        }
    }
}

extern "C" void kernel_launch(void* const* d_in, const int* in_sizes, int n_in,
                              void* d_out, int out_size, void* d_ws, size_t ws_size,
                              hipStream_t stream) {
    const float* zd = (const float*)d_in[0];
    const float* zp = (const float*)d_in[1];
    const int*   eli = (const int*)d_in[2];
    const float* W1 = (const float*)d_in[3];
    const float* b1 = (const float*)d_in[4];
    const float* W2 = (const float*)d_in[5];
    const float* b2 = (const float*)d_in[6];
    float* out = (float*)d_out;

    const int E  = in_sizes[2] / 2;
    const int nd = in_sizes[0];        // N_DRUG * 128
    const int np = in_sizes[1];        // N_PROT * 128

    const size_t need = ((size_t)nd + (size_t)np) * sizeof(unsigned short);
    if (ws_size >= need) {
        unsigned short* Hd = (unsigned short*)d_ws;
        unsigned short* Hp = Hd + nd;
        const int Nd = nd / 128, Np = np / 128;
        const int nbd = (Nd + 63) / 64, nbp = (Np + 63) / 64;
        hipLaunchKernelGGL(hprep2_kernel, dim3(nbd + nbp), dim3(512), 0, stream,
                           zd, zp, W1, b1, Hd, Hp, Nd, Np, nbd);
        hipLaunchKernelGGL(edge_kernel, dim3(4096), dim3(256), 0, stream,
                           Hd, Hp, eli, W2, b2, out, E);
    } else {
        const int nTiles = (E + TE - 1) / TE;
        hipLaunchKernelGGL(ec_fallback, dim3(2048), dim3(512), 0, stream,
                           zd, zp, eli, W1, b1, W2, b2, out, E, nTiles);
    }
}